// Round 18
// baseline (737.712 us; speedup 1.0000x reference)
//
#include <hip/hip_runtime.h>
#include <hip/hip_bf16.h>
#include <cstddef>
#include <cstdint>

constexpr int T  = 2048;
constexpr int B  = 4;
constexpr int C  = 1024;
constexpr int H  = 16;
constexpr int DK = 64;
constexpr int M  = T * B;   // 8192
constexpr int NT = T / 64;  // 32 KV tiles

typedef __attribute__((ext_vector_type(8))) short bf16x8;
typedef __attribute__((ext_vector_type(4))) float f32x4;
typedef __attribute__((ext_vector_type(4))) unsigned short u16x4;
typedef __attribute__((ext_vector_type(8))) unsigned short u16x8;

__device__ inline unsigned short f2bf(float f) {
    union { float f; uint32_t u; } v; v.f = f;
    uint32_t u = v.u + 0x7fff + ((v.u >> 16) & 1);  // RNE
    return (unsigned short)(u >> 16);
}
__device__ inline float bf2f(unsigned short h) {
    union { uint32_t u; float f; } v; v.u = (uint32_t)h << 16;
    return v.f;
}
// HW packed f32->bf16 pair (no builtin on gfx950; T12 recipe)
__device__ inline uint32_t cvtpk_bf16(float lo, float hi) {
    uint32_t r;
    asm("v_cvt_pk_bf16_f32 %0, %1, %2" : "=v"(r) : "v"(lo), "v"(hi));
    return r;
}
// compiler-level full memory fence (no instruction emitted)
__device__ inline void cfence() { asm volatile("" ::: "memory"); }

// Raw workgroup barrier WITHOUT the vmcnt(0) drain __syncthreads emits.
__device__ inline void block_sync_lds() {
    __builtin_amdgcn_sched_barrier(0);
    asm volatile("s_waitcnt lgkmcnt(0)" ::: "memory");
    __builtin_amdgcn_sched_barrier(0);
    __builtin_amdgcn_s_barrier();
    __builtin_amdgcn_sched_barrier(0);
}

// global -> LDS direct DMA, 16B per lane.
__device__ inline void gload_lds16(const void* g, void* l) {
    auto gp = reinterpret_cast<const __attribute__((address_space(1))) char*>(
        reinterpret_cast<uintptr_t>(g));
    auto lp = reinterpret_cast<__attribute__((address_space(3))) char*>(
        reinterpret_cast<uintptr_t>(l));
    __builtin_amdgcn_global_load_lds(gp, lp, 16, 0, 0);
}

// ---------------------------------------------------------------------------
// Input converter (memory-bound, HBM floor) — unchanged.
// ---------------------------------------------------------------------------
__global__ __launch_bounds__(256) void convert_in(const float* __restrict__ q,
                                                  const float* __restrict__ k,
                                                  const float* __restrict__ v,
                                                  unsigned short* __restrict__ dq,
                                                  unsigned short* __restrict__ dk2,
                                                  unsigned short* __restrict__ dv) {
    const float* s; unsigned short* d;
    if (blockIdx.y == 0) { s = q; d = dq; }
    else if (blockIdx.y == 1) { s = k; d = dk2; }
    else { s = v; d = dv; }
    const size_t i = ((size_t)blockIdx.x * 256 + threadIdx.x) * 8;
    const float4 a = *(const float4*)(s + i);
    const float4 b = *(const float4*)(s + i + 4);
    u16x8 o;
    o[0] = f2bf(a.x); o[1] = f2bf(a.y); o[2] = f2bf(a.z); o[3] = f2bf(a.w);
    o[4] = f2bf(b.x); o[5] = f2bf(b.y); o[6] = f2bf(b.z); o[7] = f2bf(b.w);
    *(u16x8*)(d + i) = o;
}

// ---------------------------------------------------------------------------
// Fused weight converter (R17): y=0..2 -> Wq/Wk/Wv into WB; y=3 -> Wo hi/lo.
// ---------------------------------------------------------------------------
__global__ __launch_bounds__(256) void convert_weights(
        const float* __restrict__ wq, const float* __restrict__ wk,
        const float* __restrict__ wv, const float* __restrict__ wo,
        unsigned short* __restrict__ wb,
        unsigned short* __restrict__ hi, unsigned short* __restrict__ lo) {
    const int y = blockIdx.y;
    const size_t i = ((size_t)blockIdx.x * 256 + threadIdx.x) * 8;
    if (y < 3) {
        const float* s = y == 0 ? wq : (y == 1 ? wk : wv);
        unsigned short* d = wb + (size_t)y * C * C;
        const float4 a = *(const float4*)(s + i);
        const float4 b = *(const float4*)(s + i + 4);
        u16x8 o;
        o[0] = f2bf(a.x); o[1] = f2bf(a.y); o[2] = f2bf(a.z); o[3] = f2bf(a.w);
        o[4] = f2bf(b.x); o[5] = f2bf(b.y); o[6] = f2bf(b.z); o[7] = f2bf(b.w);
        *(u16x8*)(d + i) = o;
    } else {
#pragma unroll
        for (int j = 0; j < 8; j++) {
            const float x = wo[i + j];
            const unsigned short h = f2bf(x);
            hi[i + j] = h;
            lo[i + j] = f2bf(x - bf2f(h));
        }
    }
}

// ---------------------------------------------------------------------------
// Fused QKV projection GEMM — R11-exact (at m97-structure ceiling ~900 TF).
// ---------------------------------------------------------------------------
__global__ __launch_bounds__(256) void qkv_gemm(
        const unsigned short* __restrict__ Aq,
        const unsigned short* __restrict__ Ak,
        const unsigned short* __restrict__ Av,
        const unsigned short* __restrict__ W,
        const float* __restrict__ bq, const float* __restrict__ bk,
        const float* __restrict__ bv,
        unsigned short* __restrict__ Qb, unsigned short* __restrict__ Kb,
        unsigned short* __restrict__ Vb) {
    __shared__ __align__(16) unsigned short As[128][32];
    __shared__ __align__(16) unsigned short Ws[128][32];

    const int tid = threadIdx.x;
    const int m0 = blockIdx.x * 128;
    const int n0 = blockIdx.y * 128;
    const int w = tid >> 6, lane = tid & 63;
    const int g = lane >> 4, c16 = lane & 15;
    const int wr = (w >> 1) * 64, wc = (w & 1) * 64;

    const int which = n0 >> 10;  // 0=Q 1=K 2=V (no straddle)
    const unsigned short* A = which == 0 ? Aq : (which == 1 ? Ak : Av);

    f32x4 acc[4][4] = {};

    for (int k0 = 0; k0 < C; k0 += 32) {
        __syncthreads();
#pragma unroll
        for (int half = 0; half < 2; half++) {
            const int chunk = tid + half * 256;       // 0..511
            const int r = chunk >> 2, s = chunk & 3;  // row, 16B slot
            gload_lds16(A + (size_t)(m0 + r) * C + k0 + s * 8,
                        (char*)&As[0][0] + chunk * 16);
            gload_lds16(W + (size_t)(n0 + r) * C + k0 + s * 8,
                        (char*)&Ws[0][0] + chunk * 16);
        }
        __syncthreads();

        bf16x8 af[4], bfr[4];
#pragma unroll
        for (int mf = 0; mf < 4; mf++)
            af[mf] = *(const bf16x8*)&As[wr + mf * 16 + c16][g * 8];
#pragma unroll
        for (int nf = 0; nf < 4; nf++)
            bfr[nf] = *(const bf16x8*)&Ws[wc + nf * 16 + c16][g * 8];
#pragma unroll
        for (int mf = 0; mf < 4; mf++)
#pragma unroll
            for (int nf = 0; nf < 4; nf++)
                acc[mf][nf] = __builtin_amdgcn_mfma_f32_16x16x32_bf16(
                    af[mf], bfr[nf], acc[mf][nf], 0, 0, 0);
    }

    unsigned short* dst = which == 0 ? Qb : (which == 1 ? Kb : Vb);
    const float* bias = which == 0 ? bq : (which == 1 ? bk : bv);
    const float scale = which == 0 ? 0.180336889f : 1.0f;  // 0.125*log2(e) | 1

#pragma unroll
    for (int mf = 0; mf < 4; mf++) {
#pragma unroll
        for (int nf = 0; nf < 4; nf++) {
            const int n = n0 + wc + nf * 16 + c16;
            const int c = n & 1023;
            const int hh = c >> 6, dk = c & 63;
            const float bval = bias[c];
#pragma unroll
            for (int r = 0; r < 4; r++) {
                const int m = m0 + wr + mf * 16 + g * 4 + r;
                const int t = m >> 2, bb = m & 3;             // m = t*B + b
                dst[((size_t)(bb * H + hh) * T + t) * DK + dk] =
                    f2bf((acc[mf][nf][r] + bval) * scale);
            }
        }
    }
}

// ---------------------------------------------------------------------------
// Output projection, bf16x3 (R7/R11 passing structure).
// ---------------------------------------------------------------------------
__global__ __launch_bounds__(256) void oproj_gemm(
        const unsigned short* __restrict__ Xh, const unsigned short* __restrict__ Xl,
        const unsigned short* __restrict__ Wh, const unsigned short* __restrict__ Wl,
        const float* __restrict__ bo, float* __restrict__ out) {
    __shared__ __align__(16) unsigned short Ahs[128][32];
    __shared__ __align__(16) unsigned short Als[128][32];
    __shared__ __align__(16) unsigned short Bhs[128][32];
    __shared__ __align__(16) unsigned short Bls[128][32];

    const int tid = threadIdx.x;
    const int m0 = blockIdx.x * 128;
    const int n0 = blockIdx.y * 128;
    const int w = tid >> 6, lane = tid & 63;
    const int g = lane >> 4, c16 = lane & 15;
    const int wr = (w >> 1) * 64, wc = (w & 1) * 64;

    f32x4 acc[4][4] = {};

    for (int k0 = 0; k0 < C; k0 += 32) {
        __syncthreads();
#pragma unroll
        for (int half = 0; half < 2; half++) {
            const int chunk = tid + half * 256;
            const int r = chunk >> 2, s = chunk & 3;
            const size_t goffA = (size_t)(m0 + r) * C + k0 + s * 8;
            const size_t goffB = (size_t)(n0 + r) * C + k0 + s * 8;
            gload_lds16(Xh + goffA, (char*)&Ahs[0][0] + chunk * 16);
            gload_lds16(Xl + goffA, (char*)&Als[0][0] + chunk * 16);
            gload_lds16(Wh + goffB, (char*)&Bhs[0][0] + chunk * 16);
            gload_lds16(Wl + goffB, (char*)&Bls[0][0] + chunk * 16);
        }
        __syncthreads();

        bf16x8 ah[4], al[4];
#pragma unroll
        for (int mf = 0; mf < 4; mf++) {
            ah[mf] = *(const bf16x8*)&Ahs[wr + mf * 16 + c16][g * 8];
            al[mf] = *(const bf16x8*)&Als[wr + mf * 16 + c16][g * 8];
        }
#pragma unroll
        for (int nf = 0; nf < 4; nf++) {
            const bf16x8 wh = *(const bf16x8*)&Bhs[wc + nf * 16 + c16][g * 8];
            const bf16x8 wl = *(const bf16x8*)&Bls[wc + nf * 16 + c16][g * 8];
#pragma unroll
            for (int mf = 0; mf < 4; mf++) {
                acc[mf][nf] = __builtin_amdgcn_mfma_f32_16x16x32_bf16(ah[mf], wh, acc[mf][nf], 0, 0, 0);
                acc[mf][nf] = __builtin_amdgcn_mfma_f32_16x16x32_bf16(al[mf], wh, acc[mf][nf], 0, 0, 0);
                acc[mf][nf] = __builtin_amdgcn_mfma_f32_16x16x32_bf16(ah[mf], wl, acc[mf][nf], 0, 0, 0);
            }
        }
    }

#pragma unroll
    for (int mf = 0; mf < 4; mf++) {
#pragma unroll
        for (int nf = 0; nf < 4; nf++) {
            const int n = n0 + wc + nf * 16 + c16;
            const float bval = bo[n];
#pragma unroll
            for (int r = 0; r < 4; r++) {
                const int m = m0 + wr + mf * 16 + g * 4 + r;  // m = b*T + t
                const int t = m & 2047, bb = m >> 11;
                out[((size_t)t * B + bb) * C + n] = acc[mf][nf][r] + bval;
            }
        }
    }
}

// ---------------------------------------------------------------------------
// Flash attention v10 = R11 champion inner loop with LDS shrunk to 40 KB via
// unpadded 64-short (128 B) rows + T2 XOR swizzle (byte ^= (row&7)<<4, both
// write AND read sides). 40960 B x 4 = 160 KB exactly -> 4 blocks/CU: the
// 1024-block grid now runs in ONE residency wave (was 3/CU -> 768 + 256-tail
// at 1/3 utilization). __launch_bounds__(256,4) caps VGPR at 128 (now 120).
// Swizzle identities used: frag/Pl reads have row&7 == c16&7 -> one `sw`
// per lane; V writes row&7 == j (compile-time); K writes (skr&7)<<4.
// ---------------------------------------------------------------------------
__global__ __launch_bounds__(256, 4) void attn_mfma(const unsigned short* __restrict__ Q,
                                                    const unsigned short* __restrict__ K,
                                                    const unsigned short* __restrict__ V,
                                                    const int* __restrict__ mask,
                                                    unsigned short* __restrict__ Xh,
                                                    unsigned short* __restrict__ Xl) {
    __shared__ __align__(16) char KsB[2][8192];   // [64 rows][128 B] swizzled
    __shared__ __align__(16) char VtB[2][8192];   // transposed V, swizzled
    __shared__ __align__(16) char PlB[4][2048];   // per-wave [16 rows][128 B]

    const int b = blockIdx.z, h = blockIdx.y;
    const int q0 = blockIdx.x * 128;
    const int tid = threadIdx.x;
    const int wl = tid >> 6;
    const int lane = tid & 63;
    const int g = lane >> 4;
    const int c16 = lane & 15;
    const int sw = (c16 & 7) << 4;    // read-side swizzle (row&7 == c16&7)

    const size_t bh = (size_t)(b * H + h) * T * DK;
    const unsigned short* Qg = Q + bh;
    const unsigned short* Kg = K + bh;
    const unsigned short* Vg = V + bh;
    const int* mb = mask + b * T;

    bf16x8 qf[2][2];
#pragma unroll
    for (int qs = 0; qs < 2; qs++)
#pragma unroll
        for (int sl = 0; sl < 2; sl++)
            qf[qs][sl] = *(const bf16x8*)(Qg +
                (size_t)(q0 + wl * 32 + qs * 16 + c16) * DK + g * 8 + sl * 32);

    f32x4 o[2][4] = {};
    float lrow[2] = {0.0f, 0.0f};

    const int skr = tid >> 3;          // K staging row 0..31 (+32 second chunk)
    const int skb = (tid & 7) * 16;    // K staging byte-in-row (16B slot)
    const int swk = (skr & 7) << 4;    // K staging swizzle ((skr+32)&7 == skr&7)
    const int kp = tid & 31, dc = tid >> 5;
    uint4 kra, krb; u16x8 va, vb; int mw;

#define ISSUE(kv0)                                                              \
    do {                                                                        \
        kra = *(const uint4*)(Kg + (size_t)((kv0) + skr) * DK + (skb >> 1));    \
        krb = *(const uint4*)(Kg + (size_t)((kv0) + skr + 32) * DK + (skb >> 1)); \
        va  = *(const u16x8*)(Vg + (size_t)((kv0) + 2 * kp) * DK + dc * 8);     \
        vb  = *(const u16x8*)(Vg + (size_t)((kv0) + 2 * kp + 1) * DK + dc * 8); \
        mw  = mb[(kv0) + lane];                                                 \
    } while (0)

    ISSUE(0);

    for (int kt = 0; kt < NT; ++kt) {
        const int buf = kt & 1;

        const unsigned long long mbits = __ballot(mw != 0);
        // K rows skr, skr+32: swizzled 16B slot
        *(uint4*)(KsB[buf] + skr * 128 + (skb ^ swk)) = kra;
        *(uint4*)(KsB[buf] + (skr + 32) * 128 + (skb ^ swk)) = krb;
        // V transposed: row = dc*8+j (row&7 == j), u32 at byte 4*kp
#pragma unroll
        for (int j = 0; j < 8; j++) {
            *(uint32_t*)(VtB[buf] + (dc * 8 + j) * 128 + ((4 * kp) ^ (j << 4))) =
                (uint32_t)(unsigned short)va[j] | ((uint32_t)(unsigned short)vb[j] << 16);
        }
        if (kt + 1 < NT) ISSUE((kt + 1) * 64);

        block_sync_lds();

        // fragments: row = t*16 + c16 -> swizzle `sw`; byte-in-row g*16+sl*64
        bf16x8 kf[4][2], vf[4][2];
#pragma unroll
        for (int t = 0; t < 4; t++)
#pragma unroll
            for (int sl = 0; sl < 2; sl++) {
                kf[t][sl] = *(const bf16x8*)(KsB[buf] + (t * 16 + c16) * 128 +
                                             ((g * 16 + sl * 64) ^ sw));
                vf[t][sl] = *(const bf16x8*)(VtB[buf] + (t * 16 + c16) * 128 +
                                             ((g * 16 + sl * 64) ^ sw));
            }

#pragma unroll
        for (int qs = 0; qs < 2; qs++) {
            f32x4 s4[4];
#pragma unroll
            for (int t = 0; t < 4; t++) {
                f32x4 acc = {0.f, 0.f, 0.f, 0.f};
                acc = __builtin_amdgcn_mfma_f32_16x16x32_bf16(kf[t][0], qf[qs][0], acc, 0, 0, 0);
                acc = __builtin_amdgcn_mfma_f32_16x16x32_bf16(kf[t][1], qf[qs][1], acc, 0, 0, 0);
                s4[t] = acc;
            }

            float rs = 0.0f;
#pragma unroll
            for (int t = 0; t < 4; t++)
#pragma unroll
                for (int r = 0; r < 4; r++) {
                    float p = __builtin_amdgcn_exp2f(s4[t][r]);
                    const int key = 16 * t + 4 * g + r;
                    p = ((mbits >> key) & 1ull) ? 0.0f : p;
                    s4[t][r] = p;
                    rs += p;
                }
            rs += __shfl_xor(rs, 16);
            rs += __shfl_xor(rs, 32);
            lrow[qs] += rs;

            // P row -> wave-private swizzled strip -> B-fragments
            cfence();
#pragma unroll
            for (int t = 0; t < 4; t++)
#pragma unroll
                for (int rr = 0; rr < 2; rr++) {
                    const uint32_t wv = cvtpk_bf16(s4[t][2 * rr], s4[t][2 * rr + 1]);
                    *(uint32_t*)(PlB[wl] + c16 * 128 +
                                 ((32 * t + 8 * g + 4 * rr) ^ sw)) = wv;
                }
            cfence();
            bf16x8 pa[2];
            pa[0] = *(const bf16x8*)(PlB[wl] + c16 * 128 + ((g * 16) ^ sw));
            pa[1] = *(const bf16x8*)(PlB[wl] + c16 * 128 + ((g * 16 + 64) ^ sw));
            cfence();

#pragma unroll
            for (int td = 0; td < 4; td++) {
                o[qs][td] = __builtin_amdgcn_mfma_f32_16x16x32_bf16(vf[td][0], pa[0], o[qs][td], 0, 0, 0);
                o[qs][td] = __builtin_amdgcn_mfma_f32_16x16x32_bf16(vf[td][1], pa[1], o[qs][td], 0, 0, 0);
            }
        }
    }
#undef ISSUE

#pragma unroll
    for (int qs = 0; qs < 2; qs++) {
        const float inv = 1.0f / lrow[qs];
        const int qq = q0 + wl * 32 + qs * 16 + c16;
#pragma unroll
        for (int td = 0; td < 4; td++) {
            u16x4 hi4, lo4;
#pragma unroll
            for (int r = 0; r < 4; r++) {
                const float val = o[qs][td][r] * inv;
                const unsigned short hv = f2bf(val);
                hi4[r] = hv;
                lo4[r] = f2bf(val - bf2f(hv));
            }
            const size_t idx = ((size_t)b * T + qq) * C + h * DK + td * 16 + 4 * g;
            *(u16x4*)(Xh + idx) = hi4;
            *(u16x4*)(Xl + idx) = lo4;
        }
    }
}

// ---------------------------------------------------------------------------
extern "C" void kernel_launch(void* const* d_in, const int* in_sizes, int n_in,
                              void* d_out, int out_size, void* d_ws, size_t ws_size,
                              hipStream_t stream) {
    const float* query = (const float*)d_in[0];
    const float* key   = (const float*)d_in[1];
    const float* value = (const float*)d_in[2];
    const int*   kpm   = (const int*)d_in[3];
    const float* Wq = (const float*)d_in[4];
    const float* bq = (const float*)d_in[5];
    const float* Wk = (const float*)d_in[6];
    const float* bk = (const float*)d_in[7];
    const float* Wv = (const float*)d_in[8];
    const float* bv = (const float*)d_in[9];
    const float* Wo = (const float*)d_in[10];
    const float* bo = (const float*)d_in[11];

    constexpr size_t MB = 1u << 20;
    char* w8 = (char*)d_ws;
    unsigned short* Qa  = (unsigned short*)(w8 + 0 * MB);   // reused as Xh
    unsigned short* Ka  = (unsigned short*)(w8 + 16 * MB);  // reused as Xl
    unsigned short* Va  = (unsigned short*)(w8 + 32 * MB);
    unsigned short* WB  = (unsigned short*)(w8 + 48 * MB);
    unsigned short* WoH = (unsigned short*)(w8 + 54 * MB);
    unsigned short* WoL = (unsigned short*)(w8 + 56 * MB);
    unsigned short* Qb  = (unsigned short*)(w8 + 64 * MB);
    unsigned short* Kb  = (unsigned short*)(w8 + 80 * MB);
    unsigned short* Vb  = (unsigned short*)(w8 + 96 * MB);
    unsigned short* XhB = Qa;
    unsigned short* XlB = Ka;

    const dim3 blk(256);

    convert_in<<<dim3(4096, 3), blk, 0, stream>>>(query, key, value, Qa, Ka, Va);
    convert_weights<<<dim3(512, 4), blk, 0, stream>>>(Wq, Wk, Wv, Wo,
                                                      WB, WoH, WoL);

    qkv_gemm<<<dim3(M / 128, 3 * C / 128), blk, 0, stream>>>(Qa, Ka, Va, WB,
                                                             bq, bk, bv,
                                                             Qb, Kb, Vb);

    attn_mfma<<<dim3(T / 128, H, B), blk, 0, stream>>>(Qb, Kb, Vb, kpm, XhB, XlB);

    oproj_gemm<<<dim3(M / 128, C / 128), blk, 0, stream>>>(XhB, XlB, WoH, WoL,
                                                           bo, (float*)d_out);
}

// Round 19
// 263.462 us; speedup vs baseline: 2.8001x; 2.8001x over previous
//
#include <hip/hip_runtime.h>
#include <hip/hip_bf16.h>
#include <cstddef>
#include <cstdint>

constexpr int T  = 2048;
constexpr int B  = 4;
constexpr int C  = 1024;
constexpr int H  = 16;
constexpr int DK = 64;
constexpr int M  = T * B;   // 8192
constexpr int NT = T / 64;  // 32 KV tiles

typedef __attribute__((ext_vector_type(8))) short bf16x8;
typedef __attribute__((ext_vector_type(4))) float f32x4;
typedef __attribute__((ext_vector_type(4))) unsigned short u16x4;
typedef __attribute__((ext_vector_type(8))) unsigned short u16x8;

__device__ inline unsigned short f2bf(float f) {
    union { float f; uint32_t u; } v; v.f = f;
    uint32_t u = v.u + 0x7fff + ((v.u >> 16) & 1);  // RNE
    return (unsigned short)(u >> 16);
}
__device__ inline float bf2f(unsigned short h) {
    union { uint32_t u; float f; } v; v.u = (uint32_t)h << 16;
    return v.f;
}
// HW packed f32->bf16 pair (no builtin on gfx950; T12 recipe)
__device__ inline uint32_t cvtpk_bf16(float lo, float hi) {
    uint32_t r;
    asm("v_cvt_pk_bf16_f32 %0, %1, %2" : "=v"(r) : "v"(lo), "v"(hi));
    return r;
}
// compiler-level full memory fence (no instruction emitted)
__device__ inline void cfence() { asm volatile("" ::: "memory"); }

// Raw workgroup barrier WITHOUT the vmcnt(0) drain __syncthreads emits.
__device__ inline void block_sync_lds() {
    __builtin_amdgcn_sched_barrier(0);
    asm volatile("s_waitcnt lgkmcnt(0)" ::: "memory");
    __builtin_amdgcn_sched_barrier(0);
    __builtin_amdgcn_s_barrier();
    __builtin_amdgcn_sched_barrier(0);
}

// global -> LDS direct DMA, 16B per lane.
__device__ inline void gload_lds16(const void* g, void* l) {
    auto gp = reinterpret_cast<const __attribute__((address_space(1))) char*>(
        reinterpret_cast<uintptr_t>(g));
    auto lp = reinterpret_cast<__attribute__((address_space(3))) char*>(
        reinterpret_cast<uintptr_t>(l));
    __builtin_amdgcn_global_load_lds(gp, lp, 16, 0, 0);
}

// ---------------------------------------------------------------------------
// Input converter (memory-bound, HBM floor) — unchanged.
// ---------------------------------------------------------------------------
__global__ __launch_bounds__(256) void convert_in(const float* __restrict__ q,
                                                  const float* __restrict__ k,
                                                  const float* __restrict__ v,
                                                  unsigned short* __restrict__ dq,
                                                  unsigned short* __restrict__ dk2,
                                                  unsigned short* __restrict__ dv) {
    const float* s; unsigned short* d;
    if (blockIdx.y == 0) { s = q; d = dq; }
    else if (blockIdx.y == 1) { s = k; d = dk2; }
    else { s = v; d = dv; }
    const size_t i = ((size_t)blockIdx.x * 256 + threadIdx.x) * 8;
    const float4 a = *(const float4*)(s + i);
    const float4 b = *(const float4*)(s + i + 4);
    u16x8 o;
    o[0] = f2bf(a.x); o[1] = f2bf(a.y); o[2] = f2bf(a.z); o[3] = f2bf(a.w);
    o[4] = f2bf(b.x); o[5] = f2bf(b.y); o[6] = f2bf(b.z); o[7] = f2bf(b.w);
    *(u16x8*)(d + i) = o;
}

// ---------------------------------------------------------------------------
// Fused weight converter (R17): y=0..2 -> Wq/Wk/Wv into WB; y=3 -> Wo hi/lo.
// ---------------------------------------------------------------------------
__global__ __launch_bounds__(256) void convert_weights(
        const float* __restrict__ wq, const float* __restrict__ wk,
        const float* __restrict__ wv, const float* __restrict__ wo,
        unsigned short* __restrict__ wb,
        unsigned short* __restrict__ hi, unsigned short* __restrict__ lo) {
    const int y = blockIdx.y;
    const size_t i = ((size_t)blockIdx.x * 256 + threadIdx.x) * 8;
    if (y < 3) {
        const float* s = y == 0 ? wq : (y == 1 ? wk : wv);
        unsigned short* d = wb + (size_t)y * C * C;
        const float4 a = *(const float4*)(s + i);
        const float4 b = *(const float4*)(s + i + 4);
        u16x8 o;
        o[0] = f2bf(a.x); o[1] = f2bf(a.y); o[2] = f2bf(a.z); o[3] = f2bf(a.w);
        o[4] = f2bf(b.x); o[5] = f2bf(b.y); o[6] = f2bf(b.z); o[7] = f2bf(b.w);
        *(u16x8*)(d + i) = o;
    } else {
#pragma unroll
        for (int j = 0; j < 8; j++) {
            const float x = wo[i + j];
            const unsigned short h = f2bf(x);
            hi[i + j] = h;
            lo[i + j] = f2bf(x - bf2f(h));
        }
    }
}

// ---------------------------------------------------------------------------
// Fused QKV projection GEMM — R11-exact (at m97-structure ceiling ~900 TF).
// ---------------------------------------------------------------------------
__global__ __launch_bounds__(256) void qkv_gemm(
        const unsigned short* __restrict__ Aq,
        const unsigned short* __restrict__ Ak,
        const unsigned short* __restrict__ Av,
        const unsigned short* __restrict__ W,
        const float* __restrict__ bq, const float* __restrict__ bk,
        const float* __restrict__ bv,
        unsigned short* __restrict__ Qb, unsigned short* __restrict__ Kb,
        unsigned short* __restrict__ Vb) {
    __shared__ __align__(16) unsigned short As[128][32];
    __shared__ __align__(16) unsigned short Ws[128][32];

    const int tid = threadIdx.x;
    const int m0 = blockIdx.x * 128;
    const int n0 = blockIdx.y * 128;
    const int w = tid >> 6, lane = tid & 63;
    const int g = lane >> 4, c16 = lane & 15;
    const int wr = (w >> 1) * 64, wc = (w & 1) * 64;

    const int which = n0 >> 10;  // 0=Q 1=K 2=V (no straddle)
    const unsigned short* A = which == 0 ? Aq : (which == 1 ? Ak : Av);

    f32x4 acc[4][4] = {};

    for (int k0 = 0; k0 < C; k0 += 32) {
        __syncthreads();
#pragma unroll
        for (int half = 0; half < 2; half++) {
            const int chunk = tid + half * 256;       // 0..511
            const int r = chunk >> 2, s = chunk & 3;  // row, 16B slot
            gload_lds16(A + (size_t)(m0 + r) * C + k0 + s * 8,
                        (char*)&As[0][0] + chunk * 16);
            gload_lds16(W + (size_t)(n0 + r) * C + k0 + s * 8,
                        (char*)&Ws[0][0] + chunk * 16);
        }
        __syncthreads();

        bf16x8 af[4], bfr[4];
#pragma unroll
        for (int mf = 0; mf < 4; mf++)
            af[mf] = *(const bf16x8*)&As[wr + mf * 16 + c16][g * 8];
#pragma unroll
        for (int nf = 0; nf < 4; nf++)
            bfr[nf] = *(const bf16x8*)&Ws[wc + nf * 16 + c16][g * 8];
#pragma unroll
        for (int mf = 0; mf < 4; mf++)
#pragma unroll
            for (int nf = 0; nf < 4; nf++)
                acc[mf][nf] = __builtin_amdgcn_mfma_f32_16x16x32_bf16(
                    af[mf], bfr[nf], acc[mf][nf], 0, 0, 0);
    }

    unsigned short* dst = which == 0 ? Qb : (which == 1 ? Kb : Vb);
    const float* bias = which == 0 ? bq : (which == 1 ? bk : bv);
    const float scale = which == 0 ? 0.180336889f : 1.0f;  // 0.125*log2(e) | 1

#pragma unroll
    for (int mf = 0; mf < 4; mf++) {
#pragma unroll
        for (int nf = 0; nf < 4; nf++) {
            const int n = n0 + wc + nf * 16 + c16;
            const int c = n & 1023;
            const int hh = c >> 6, dk = c & 63;
            const float bval = bias[c];
#pragma unroll
            for (int r = 0; r < 4; r++) {
                const int m = m0 + wr + mf * 16 + g * 4 + r;
                const int t = m >> 2, bb = m & 3;             // m = t*B + b
                dst[((size_t)(bb * H + hh) * T + t) * DK + dk] =
                    f2bf((acc[mf][nf][r] + bval) * scale);
            }
        }
    }
}

// ---------------------------------------------------------------------------
// Output projection, bf16x3 (R7/R11 passing structure).
// ---------------------------------------------------------------------------
__global__ __launch_bounds__(256) void oproj_gemm(
        const unsigned short* __restrict__ Xh, const unsigned short* __restrict__ Xl,
        const unsigned short* __restrict__ Wh, const unsigned short* __restrict__ Wl,
        const float* __restrict__ bo, float* __restrict__ out) {
    __shared__ __align__(16) unsigned short Ahs[128][32];
    __shared__ __align__(16) unsigned short Als[128][32];
    __shared__ __align__(16) unsigned short Bhs[128][32];
    __shared__ __align__(16) unsigned short Bls[128][32];

    const int tid = threadIdx.x;
    const int m0 = blockIdx.x * 128;
    const int n0 = blockIdx.y * 128;
    const int w = tid >> 6, lane = tid & 63;
    const int g = lane >> 4, c16 = lane & 15;
    const int wr = (w >> 1) * 64, wc = (w & 1) * 64;

    f32x4 acc[4][4] = {};

    for (int k0 = 0; k0 < C; k0 += 32) {
        __syncthreads();
#pragma unroll
        for (int half = 0; half < 2; half++) {
            const int chunk = tid + half * 256;
            const int r = chunk >> 2, s = chunk & 3;
            const size_t goffA = (size_t)(m0 + r) * C + k0 + s * 8;
            const size_t goffB = (size_t)(n0 + r) * C + k0 + s * 8;
            gload_lds16(Xh + goffA, (char*)&Ahs[0][0] + chunk * 16);
            gload_lds16(Xl + goffA, (char*)&Als[0][0] + chunk * 16);
            gload_lds16(Wh + goffB, (char*)&Bhs[0][0] + chunk * 16);
            gload_lds16(Wl + goffB, (char*)&Bls[0][0] + chunk * 16);
        }
        __syncthreads();

        bf16x8 ah[4], al[4];
#pragma unroll
        for (int mf = 0; mf < 4; mf++) {
            ah[mf] = *(const bf16x8*)&Ahs[wr + mf * 16 + c16][g * 8];
            al[mf] = *(const bf16x8*)&Als[wr + mf * 16 + c16][g * 8];
        }
#pragma unroll
        for (int nf = 0; nf < 4; nf++) {
            const bf16x8 wh = *(const bf16x8*)&Bhs[wc + nf * 16 + c16][g * 8];
            const bf16x8 wl = *(const bf16x8*)&Bls[wc + nf * 16 + c16][g * 8];
#pragma unroll
            for (int mf = 0; mf < 4; mf++) {
                acc[mf][nf] = __builtin_amdgcn_mfma_f32_16x16x32_bf16(ah[mf], wh, acc[mf][nf], 0, 0, 0);
                acc[mf][nf] = __builtin_amdgcn_mfma_f32_16x16x32_bf16(al[mf], wh, acc[mf][nf], 0, 0, 0);
                acc[mf][nf] = __builtin_amdgcn_mfma_f32_16x16x32_bf16(ah[mf], wl, acc[mf][nf], 0, 0, 0);
            }
        }
    }

#pragma unroll
    for (int mf = 0; mf < 4; mf++) {
#pragma unroll
        for (int nf = 0; nf < 4; nf++) {
            const int n = n0 + wc + nf * 16 + c16;
            const float bval = bo[n];
#pragma unroll
            for (int r = 0; r < 4; r++) {
                const int m = m0 + wr + mf * 16 + g * 4 + r;  // m = b*T + t
                const int t = m & 2047, bb = m >> 11;
                out[((size_t)t * B + bb) * C + n] = acc[mf][nf][r] + bval;
            }
        }
    }
}

// ---------------------------------------------------------------------------
// Flash attention v10b = R18's swizzled 40 KB LDS layout (correctness proven
// in R18: absmax unchanged) with the VGPR-clamping __launch_bounds__(256,4)
// REMOVED. Compiler returns to ~120 VGPR (no spills); 40960 B LDS x 4 =
// 160 KB and VGPR<=128 give 4 blocks/CU naturally -> the 1024-block grid
// runs in one residency wave (R17 ran 3/CU = 768 + 256-block tail).
// ---------------------------------------------------------------------------
__global__ __launch_bounds__(256) void attn_mfma(const unsigned short* __restrict__ Q,
                                                 const unsigned short* __restrict__ K,
                                                 const unsigned short* __restrict__ V,
                                                 const int* __restrict__ mask,
                                                 unsigned short* __restrict__ Xh,
                                                 unsigned short* __restrict__ Xl) {
    __shared__ __align__(16) char KsB[2][8192];   // [64 rows][128 B] swizzled
    __shared__ __align__(16) char VtB[2][8192];   // transposed V, swizzled
    __shared__ __align__(16) char PlB[4][2048];   // per-wave [16 rows][128 B]

    const int b = blockIdx.z, h = blockIdx.y;
    const int q0 = blockIdx.x * 128;
    const int tid = threadIdx.x;
    const int wl = tid >> 6;
    const int lane = tid & 63;
    const int g = lane >> 4;
    const int c16 = lane & 15;
    const int sw = (c16 & 7) << 4;    // read-side swizzle (row&7 == c16&7)

    const size_t bh = (size_t)(b * H + h) * T * DK;
    const unsigned short* Qg = Q + bh;
    const unsigned short* Kg = K + bh;
    const unsigned short* Vg = V + bh;
    const int* mb = mask + b * T;

    bf16x8 qf[2][2];
#pragma unroll
    for (int qs = 0; qs < 2; qs++)
#pragma unroll
        for (int sl = 0; sl < 2; sl++)
            qf[qs][sl] = *(const bf16x8*)(Qg +
                (size_t)(q0 + wl * 32 + qs * 16 + c16) * DK + g * 8 + sl * 32);

    f32x4 o[2][4] = {};
    float lrow[2] = {0.0f, 0.0f};

    const int skr = tid >> 3;          // K staging row 0..31 (+32 second chunk)
    const int skb = (tid & 7) * 16;    // K staging byte-in-row (16B slot)
    const int swk = (skr & 7) << 4;    // K staging swizzle ((skr+32)&7 == skr&7)
    const int kp = tid & 31, dc = tid >> 5;
    uint4 kra, krb; u16x8 va, vb; int mw;

#define ISSUE(kv0)                                                              \
    do {                                                                        \
        kra = *(const uint4*)(Kg + (size_t)((kv0) + skr) * DK + (skb >> 1));    \
        krb = *(const uint4*)(Kg + (size_t)((kv0) + skr + 32) * DK + (skb >> 1)); \
        va  = *(const u16x8*)(Vg + (size_t)((kv0) + 2 * kp) * DK + dc * 8);     \
        vb  = *(const u16x8*)(Vg + (size_t)((kv0) + 2 * kp + 1) * DK + dc * 8); \
        mw  = mb[(kv0) + lane];                                                 \
    } while (0)

    ISSUE(0);

    for (int kt = 0; kt < NT; ++kt) {
        const int buf = kt & 1;

        const unsigned long long mbits = __ballot(mw != 0);
        // K rows skr, skr+32: swizzled 16B slot
        *(uint4*)(KsB[buf] + skr * 128 + (skb ^ swk)) = kra;
        *(uint4*)(KsB[buf] + (skr + 32) * 128 + (skb ^ swk)) = krb;
        // V transposed: row = dc*8+j (row&7 == j), u32 at byte 4*kp
#pragma unroll
        for (int j = 0; j < 8; j++) {
            *(uint32_t*)(VtB[buf] + (dc * 8 + j) * 128 + ((4 * kp) ^ (j << 4))) =
                (uint32_t)(unsigned short)va[j] | ((uint32_t)(unsigned short)vb[j] << 16);
        }
        if (kt + 1 < NT) ISSUE((kt + 1) * 64);

        block_sync_lds();

        // fragments: row = t*16 + c16 -> swizzle `sw`; byte-in-row g*16+sl*64
        bf16x8 kf[4][2], vf[4][2];
#pragma unroll
        for (int t = 0; t < 4; t++)
#pragma unroll
            for (int sl = 0; sl < 2; sl++) {
                kf[t][sl] = *(const bf16x8*)(KsB[buf] + (t * 16 + c16) * 128 +
                                             ((g * 16 + sl * 64) ^ sw));
                vf[t][sl] = *(const bf16x8*)(VtB[buf] + (t * 16 + c16) * 128 +
                                             ((g * 16 + sl * 64) ^ sw));
            }

#pragma unroll
        for (int qs = 0; qs < 2; qs++) {
            f32x4 s4[4];
#pragma unroll
            for (int t = 0; t < 4; t++) {
                f32x4 acc = {0.f, 0.f, 0.f, 0.f};
                acc = __builtin_amdgcn_mfma_f32_16x16x32_bf16(kf[t][0], qf[qs][0], acc, 0, 0, 0);
                acc = __builtin_amdgcn_mfma_f32_16x16x32_bf16(kf[t][1], qf[qs][1], acc, 0, 0, 0);
                s4[t] = acc;
            }

            float rs = 0.0f;
#pragma unroll
            for (int t = 0; t < 4; t++)
#pragma unroll
                for (int r = 0; r < 4; r++) {
                    float p = __builtin_amdgcn_exp2f(s4[t][r]);
                    const int key = 16 * t + 4 * g + r;
                    p = ((mbits >> key) & 1ull) ? 0.0f : p;
                    s4[t][r] = p;
                    rs += p;
                }
            rs += __shfl_xor(rs, 16);
            rs += __shfl_xor(rs, 32);
            lrow[qs] += rs;

            // P row -> wave-private swizzled strip -> B-fragments
            cfence();
#pragma unroll
            for (int t = 0; t < 4; t++)
#pragma unroll
                for (int rr = 0; rr < 2; rr++) {
                    const uint32_t wv = cvtpk_bf16(s4[t][2 * rr], s4[t][2 * rr + 1]);
                    *(uint32_t*)(PlB[wl] + c16 * 128 +
                                 ((32 * t + 8 * g + 4 * rr) ^ sw)) = wv;
                }
            cfence();
            bf16x8 pa[2];
            pa[0] = *(const bf16x8*)(PlB[wl] + c16 * 128 + ((g * 16) ^ sw));
            pa[1] = *(const bf16x8*)(PlB[wl] + c16 * 128 + ((g * 16 + 64) ^ sw));
            cfence();

#pragma unroll
            for (int td = 0; td < 4; td++) {
                o[qs][td] = __builtin_amdgcn_mfma_f32_16x16x32_bf16(vf[td][0], pa[0], o[qs][td], 0, 0, 0);
                o[qs][td] = __builtin_amdgcn_mfma_f32_16x16x32_bf16(vf[td][1], pa[1], o[qs][td], 0, 0, 0);
            }
        }
    }
#undef ISSUE

#pragma unroll
    for (int qs = 0; qs < 2; qs++) {
        const float inv = 1.0f / lrow[qs];
        const int qq = q0 + wl * 32 + qs * 16 + c16;
#pragma unroll
        for (int td = 0; td < 4; td++) {
            u16x4 hi4, lo4;
#pragma unroll
            for (int r = 0; r < 4; r++) {
                const float val = o[qs][td][r] * inv;
                const unsigned short hv = f2bf(val);
                hi4[r] = hv;
                lo4[r] = f2bf(val - bf2f(hv));
            }
            const size_t idx = ((size_t)b * T + qq) * C + h * DK + td * 16 + 4 * g;
            *(u16x4*)(Xh + idx) = hi4;
            *(u16x4*)(Xl + idx) = lo4;
        }
    }
}

// ---------------------------------------------------------------------------
extern "C" void kernel_launch(void* const* d_in, const int* in_sizes, int n_in,
                              void* d_out, int out_size, void* d_ws, size_t ws_size,
                              hipStream_t stream) {
    const float* query = (const float*)d_in[0];
    const float* key   = (const float*)d_in[1];
    const float* value = (const float*)d_in[2];
    const int*   kpm   = (const int*)d_in[3];
    const float* Wq = (const float*)d_in[4];
    const float* bq = (const float*)d_in[5];
    const float* Wk = (const float*)d_in[6];
    const float* bk = (const float*)d_in[7];
    const float* Wv = (const float*)d_in[8];
    const float* bv = (const float*)d_in[9];
    const float* Wo = (const float*)d_in[10];
    const float* bo = (const float*)d_in[11];

    constexpr size_t MB = 1u << 20;
    char* w8 = (char*)d_ws;
    unsigned short* Qa  = (unsigned short*)(w8 + 0 * MB);   // reused as Xh
    unsigned short* Ka  = (unsigned short*)(w8 + 16 * MB);  // reused as Xl
    unsigned short* Va  = (unsigned short*)(w8 + 32 * MB);
    unsigned short* WB  = (unsigned short*)(w8 + 48 * MB);
    unsigned short* WoH = (unsigned short*)(w8 + 54 * MB);
    unsigned short* WoL = (unsigned short*)(w8 + 56 * MB);
    unsigned short* Qb  = (unsigned short*)(w8 + 64 * MB);
    unsigned short* Kb  = (unsigned short*)(w8 + 80 * MB);
    unsigned short* Vb  = (unsigned short*)(w8 + 96 * MB);
    unsigned short* XhB = Qa;
    unsigned short* XlB = Ka;

    const dim3 blk(256);

    convert_in<<<dim3(4096, 3), blk, 0, stream>>>(query, key, value, Qa, Ka, Va);
    convert_weights<<<dim3(512, 4), blk, 0, stream>>>(Wq, Wk, Wv, Wo,
                                                      WB, WoH, WoL);

    qkv_gemm<<<dim3(M / 128, 3 * C / 128), blk, 0, stream>>>(Qa, Ka, Va, WB,
                                                             bq, bk, bv,
                                                             Qb, Kb, Vb);

    attn_mfma<<<dim3(T / 128, H, B), blk, 0, stream>>>(Qb, Kb, Vb, kpm, XhB, XlB);

    oproj_gemm<<<dim3(M / 128, C / 128), blk, 0, stream>>>(XhB, XlB, WoH, WoL,
                                                           bo, (float*)d_out);
}

// Round 20
// 262.700 us; speedup vs baseline: 2.8082x; 1.0029x over previous
//
#include <hip/hip_runtime.h>
#include <hip/hip_bf16.h>
#include <cstddef>
#include <cstdint>

constexpr int T  = 2048;
constexpr int B  = 4;
constexpr int C  = 1024;
constexpr int H  = 16;
constexpr int DK = 64;
constexpr int M  = T * B;   // 8192
constexpr int NT = T / 64;  // 32 KV tiles

typedef __attribute__((ext_vector_type(8))) short bf16x8;
typedef __attribute__((ext_vector_type(4))) float f32x4;
typedef __attribute__((ext_vector_type(4))) unsigned short u16x4;
typedef __attribute__((ext_vector_type(8))) unsigned short u16x8;

__device__ inline unsigned short f2bf(float f) {
    union { float f; uint32_t u; } v; v.f = f;
    uint32_t u = v.u + 0x7fff + ((v.u >> 16) & 1);  // RNE
    return (unsigned short)(u >> 16);
}
__device__ inline float bf2f(unsigned short h) {
    union { uint32_t u; float f; } v; v.u = (uint32_t)h << 16;
    return v.f;
}
// HW packed f32->bf16 pair (no builtin on gfx950; T12 recipe)
__device__ inline uint32_t cvtpk_bf16(float lo, float hi) {
    uint32_t r;
    asm("v_cvt_pk_bf16_f32 %0, %1, %2" : "=v"(r) : "v"(lo), "v"(hi));
    return r;
}
// compiler-level full memory fence (no instruction emitted)
__device__ inline void cfence() { asm volatile("" ::: "memory"); }

// Raw workgroup barrier WITHOUT the vmcnt(0) drain __syncthreads emits.
__device__ inline void block_sync_lds() {
    __builtin_amdgcn_sched_barrier(0);
    asm volatile("s_waitcnt lgkmcnt(0)" ::: "memory");
    __builtin_amdgcn_sched_barrier(0);
    __builtin_amdgcn_s_barrier();
    __builtin_amdgcn_sched_barrier(0);
}

// global -> LDS direct DMA, 16B per lane.
__device__ inline void gload_lds16(const void* g, void* l) {
    auto gp = reinterpret_cast<const __attribute__((address_space(1))) char*>(
        reinterpret_cast<uintptr_t>(g));
    auto lp = reinterpret_cast<__attribute__((address_space(3))) char*>(
        reinterpret_cast<uintptr_t>(l));
    __builtin_amdgcn_global_load_lds(gp, lp, 16, 0, 0);
}

// ---------------------------------------------------------------------------
// Unified converter (one launch). Flat grid of 14336 blocks:
//   bid < 12288 : q/k/v fp32 -> bf16      (3 x 4096 blocks, 8.39M elem each)
//   bid >= 12288: Wq/Wk/Wv -> WB bf16 and Wo -> hi/lo (4 x 512 blocks)
// ---------------------------------------------------------------------------
__global__ __launch_bounds__(256) void convert_all(
        const float* __restrict__ q, const float* __restrict__ k,
        const float* __restrict__ v,
        const float* __restrict__ wq, const float* __restrict__ wk,
        const float* __restrict__ wv, const float* __restrict__ wo,
        unsigned short* __restrict__ dq, unsigned short* __restrict__ dk2,
        unsigned short* __restrict__ dv,
        unsigned short* __restrict__ wb,
        unsigned short* __restrict__ hi, unsigned short* __restrict__ lo) {
    const int bid = blockIdx.x;
    if (bid < 12288) {
        const int which = bid >> 12;            // 0..2
        const int x = bid & 4095;
        const float* s = which == 0 ? q : (which == 1 ? k : v);
        unsigned short* d = which == 0 ? dq : (which == 1 ? dk2 : dv);
        const size_t i = ((size_t)x * 256 + threadIdx.x) * 8;
        const float4 a = *(const float4*)(s + i);
        const float4 b = *(const float4*)(s + i + 4);
        u16x8 o;
        o[0] = f2bf(a.x); o[1] = f2bf(a.y); o[2] = f2bf(a.z); o[3] = f2bf(a.w);
        o[4] = f2bf(b.x); o[5] = f2bf(b.y); o[6] = f2bf(b.z); o[7] = f2bf(b.w);
        *(u16x8*)(d + i) = o;
    } else {
        const int w = bid - 12288;
        const int y = w >> 9;                   // 0..3
        const int x = w & 511;
        const size_t i = ((size_t)x * 256 + threadIdx.x) * 8;
        if (y < 3) {
            const float* s = y == 0 ? wq : (y == 1 ? wk : wv);
            unsigned short* d = wb + (size_t)y * C * C;
            const float4 a = *(const float4*)(s + i);
            const float4 b = *(const float4*)(s + i + 4);
            u16x8 o;
            o[0] = f2bf(a.x); o[1] = f2bf(a.y); o[2] = f2bf(a.z); o[3] = f2bf(a.w);
            o[4] = f2bf(b.x); o[5] = f2bf(b.y); o[6] = f2bf(b.z); o[7] = f2bf(b.w);
            *(u16x8*)(d + i) = o;
        } else {
#pragma unroll
            for (int j = 0; j < 8; j++) {
                const float x2 = wo[i + j];
                const unsigned short h = f2bf(x2);
                hi[i + j] = h;
                lo[i + j] = f2bf(x2 - bf2f(h));
            }
        }
    }
}

// ---------------------------------------------------------------------------
// Fused QKV projection GEMM — R11-exact (at m97-structure ceiling ~900 TF).
// Q scale folds 1/sqrt(DK) * log2(e) for the exp2-based softmax.
// ---------------------------------------------------------------------------
__global__ __launch_bounds__(256) void qkv_gemm(
        const unsigned short* __restrict__ Aq,
        const unsigned short* __restrict__ Ak,
        const unsigned short* __restrict__ Av,
        const unsigned short* __restrict__ W,
        const float* __restrict__ bq, const float* __restrict__ bk,
        const float* __restrict__ bv,
        unsigned short* __restrict__ Qb, unsigned short* __restrict__ Kb,
        unsigned short* __restrict__ Vb) {
    __shared__ __align__(16) unsigned short As[128][32];
    __shared__ __align__(16) unsigned short Ws[128][32];

    const int tid = threadIdx.x;
    const int m0 = blockIdx.x * 128;
    const int n0 = blockIdx.y * 128;
    const int w = tid >> 6, lane = tid & 63;
    const int g = lane >> 4, c16 = lane & 15;
    const int wr = (w >> 1) * 64, wc = (w & 1) * 64;

    const int which = n0 >> 10;  // 0=Q 1=K 2=V (no straddle)
    const unsigned short* A = which == 0 ? Aq : (which == 1 ? Ak : Av);

    f32x4 acc[4][4] = {};

    for (int k0 = 0; k0 < C; k0 += 32) {
        __syncthreads();
#pragma unroll
        for (int half = 0; half < 2; half++) {
            const int chunk = tid + half * 256;       // 0..511
            const int r = chunk >> 2, s = chunk & 3;  // row, 16B slot
            gload_lds16(A + (size_t)(m0 + r) * C + k0 + s * 8,
                        (char*)&As[0][0] + chunk * 16);
            gload_lds16(W + (size_t)(n0 + r) * C + k0 + s * 8,
                        (char*)&Ws[0][0] + chunk * 16);
        }
        __syncthreads();

        bf16x8 af[4], bfr[4];
#pragma unroll
        for (int mf = 0; mf < 4; mf++)
            af[mf] = *(const bf16x8*)&As[wr + mf * 16 + c16][g * 8];
#pragma unroll
        for (int nf = 0; nf < 4; nf++)
            bfr[nf] = *(const bf16x8*)&Ws[wc + nf * 16 + c16][g * 8];
#pragma unroll
        for (int mf = 0; mf < 4; mf++)
#pragma unroll
            for (int nf = 0; nf < 4; nf++)
                acc[mf][nf] = __builtin_amdgcn_mfma_f32_16x16x32_bf16(
                    af[mf], bfr[nf], acc[mf][nf], 0, 0, 0);
    }

    unsigned short* dst = which == 0 ? Qb : (which == 1 ? Kb : Vb);
    const float* bias = which == 0 ? bq : (which == 1 ? bk : bv);
    const float scale = which == 0 ? 0.180336889f : 1.0f;  // 0.125*log2(e) | 1

#pragma unroll
    for (int mf = 0; mf < 4; mf++) {
#pragma unroll
        for (int nf = 0; nf < 4; nf++) {
            const int n = n0 + wc + nf * 16 + c16;
            const int c = n & 1023;
            const int hh = c >> 6, dk = c & 63;
            const float bval = bias[c];
#pragma unroll
            for (int r = 0; r < 4; r++) {
                const int m = m0 + wr + mf * 16 + g * 4 + r;
                const int t = m >> 2, bb = m & 3;             // m = t*B + b
                dst[((size_t)(bb * H + hh) * T + t) * DK + dk] =
                    f2bf((acc[mf][nf][r] + bval) * scale);
            }
        }
    }
}

// ---------------------------------------------------------------------------
// Output projection, bf16x3 (R7/R11 passing structure).
// ---------------------------------------------------------------------------
__global__ __launch_bounds__(256) void oproj_gemm(
        const unsigned short* __restrict__ Xh, const unsigned short* __restrict__ Xl,
        const unsigned short* __restrict__ Wh, const unsigned short* __restrict__ Wl,
        const float* __restrict__ bo, float* __restrict__ out) {
    __shared__ __align__(16) unsigned short Ahs[128][32];
    __shared__ __align__(16) unsigned short Als[128][32];
    __shared__ __align__(16) unsigned short Bhs[128][32];
    __shared__ __align__(16) unsigned short Bls[128][32];

    const int tid = threadIdx.x;
    const int m0 = blockIdx.x * 128;
    const int n0 = blockIdx.y * 128;
    const int w = tid >> 6, lane = tid & 63;
    const int g = lane >> 4, c16 = lane & 15;
    const int wr = (w >> 1) * 64, wc = (w & 1) * 64;

    f32x4 acc[4][4] = {};

    for (int k0 = 0; k0 < C; k0 += 32) {
        __syncthreads();
#pragma unroll
        for (int half = 0; half < 2; half++) {
            const int chunk = tid + half * 256;
            const int r = chunk >> 2, s = chunk & 3;
            const size_t goffA = (size_t)(m0 + r) * C + k0 + s * 8;
            const size_t goffB = (size_t)(n0 + r) * C + k0 + s * 8;
            gload_lds16(Xh + goffA, (char*)&Ahs[0][0] + chunk * 16);
            gload_lds16(Xl + goffA, (char*)&Als[0][0] + chunk * 16);
            gload_lds16(Wh + goffB, (char*)&Bhs[0][0] + chunk * 16);
            gload_lds16(Wl + goffB, (char*)&Bls[0][0] + chunk * 16);
        }
        __syncthreads();

        bf16x8 ah[4], al[4];
#pragma unroll
        for (int mf = 0; mf < 4; mf++) {
            ah[mf] = *(const bf16x8*)&Ahs[wr + mf * 16 + c16][g * 8];
            al[mf] = *(const bf16x8*)&Als[wr + mf * 16 + c16][g * 8];
        }
#pragma unroll
        for (int nf = 0; nf < 4; nf++) {
            const bf16x8 wh = *(const bf16x8*)&Bhs[wc + nf * 16 + c16][g * 8];
            const bf16x8 wl = *(const bf16x8*)&Bls[wc + nf * 16 + c16][g * 8];
#pragma unroll
            for (int mf = 0; mf < 4; mf++) {
                acc[mf][nf] = __builtin_amdgcn_mfma_f32_16x16x32_bf16(ah[mf], wh, acc[mf][nf], 0, 0, 0);
                acc[mf][nf] = __builtin_amdgcn_mfma_f32_16x16x32_bf16(al[mf], wh, acc[mf][nf], 0, 0, 0);
                acc[mf][nf] = __builtin_amdgcn_mfma_f32_16x16x32_bf16(ah[mf], wl, acc[mf][nf], 0, 0, 0);
            }
        }
    }

#pragma unroll
    for (int mf = 0; mf < 4; mf++) {
#pragma unroll
        for (int nf = 0; nf < 4; nf++) {
            const int n = n0 + wc + nf * 16 + c16;
            const float bval = bo[n];
#pragma unroll
            for (int r = 0; r < 4; r++) {
                const int m = m0 + wr + mf * 16 + g * 4 + r;  // m = b*T + t
                const int t = m & 2047, bb = m >> 11;
                out[((size_t)t * B + bb) * C + n] = acc[mf][nf][r] + bval;
            }
        }
    }
}

// ---------------------------------------------------------------------------
// Flash attention v10b (R19 champion, 136.6 us): swizzled 40 KB LDS
// (4 blocks/CU, no grid tail), double-buffered K/V with reg-staged prefetch
// spanning one raw lgkm-only barrier per tile, swapped QK^T (lane-local
// softmax rows), exp2 with log2e folded in Q, bit-test mask zeroing,
// cvt_pk P-pack through wave-private swizzled LDS strips.
// ---------------------------------------------------------------------------
__global__ __launch_bounds__(256) void attn_mfma(const unsigned short* __restrict__ Q,
                                                 const unsigned short* __restrict__ K,
                                                 const unsigned short* __restrict__ V,
                                                 const int* __restrict__ mask,
                                                 unsigned short* __restrict__ Xh,
                                                 unsigned short* __restrict__ Xl) {
    __shared__ __align__(16) char KsB[2][8192];   // [64 rows][128 B] swizzled
    __shared__ __align__(16) char VtB[2][8192];   // transposed V, swizzled
    __shared__ __align__(16) char PlB[4][2048];   // per-wave [16 rows][128 B]

    const int b = blockIdx.z, h = blockIdx.y;
    const int q0 = blockIdx.x * 128;
    const int tid = threadIdx.x;
    const int wl = tid >> 6;
    const int lane = tid & 63;
    const int g = lane >> 4;
    const int c16 = lane & 15;
    const int sw = (c16 & 7) << 4;    // read-side swizzle (row&7 == c16&7)

    const size_t bh = (size_t)(b * H + h) * T * DK;
    const unsigned short* Qg = Q + bh;
    const unsigned short* Kg = K + bh;
    const unsigned short* Vg = V + bh;
    const int* mb = mask + b * T;

    bf16x8 qf[2][2];
#pragma unroll
    for (int qs = 0; qs < 2; qs++)
#pragma unroll
        for (int sl = 0; sl < 2; sl++)
            qf[qs][sl] = *(const bf16x8*)(Qg +
                (size_t)(q0 + wl * 32 + qs * 16 + c16) * DK + g * 8 + sl * 32);

    f32x4 o[2][4] = {};
    float lrow[2] = {0.0f, 0.0f};

    const int skr = tid >> 3;          // K staging row 0..31 (+32 second chunk)
    const int skb = (tid & 7) * 16;    // K staging byte-in-row (16B slot)
    const int swk = (skr & 7) << 4;    // K staging swizzle ((skr+32)&7 == skr&7)
    const int kp = tid & 31, dc = tid >> 5;
    uint4 kra, krb; u16x8 va, vb; int mw;

#define ISSUE(kv0)                                                              \
    do {                                                                        \
        kra = *(const uint4*)(Kg + (size_t)((kv0) + skr) * DK + (skb >> 1));    \
        krb = *(const uint4*)(Kg + (size_t)((kv0) + skr + 32) * DK + (skb >> 1)); \
        va  = *(const u16x8*)(Vg + (size_t)((kv0) + 2 * kp) * DK + dc * 8);     \
        vb  = *(const u16x8*)(Vg + (size_t)((kv0) + 2 * kp + 1) * DK + dc * 8); \
        mw  = mb[(kv0) + lane];                                                 \
    } while (0)

    ISSUE(0);

    for (int kt = 0; kt < NT; ++kt) {
        const int buf = kt & 1;

        const unsigned long long mbits = __ballot(mw != 0);
        // K rows skr, skr+32: swizzled 16B slot
        *(uint4*)(KsB[buf] + skr * 128 + (skb ^ swk)) = kra;
        *(uint4*)(KsB[buf] + (skr + 32) * 128 + (skb ^ swk)) = krb;
        // V transposed: row = dc*8+j (row&7 == j), u32 at byte 4*kp
#pragma unroll
        for (int j = 0; j < 8; j++) {
            *(uint32_t*)(VtB[buf] + (dc * 8 + j) * 128 + ((4 * kp) ^ (j << 4))) =
                (uint32_t)(unsigned short)va[j] | ((uint32_t)(unsigned short)vb[j] << 16);
        }
        if (kt + 1 < NT) ISSUE((kt + 1) * 64);

        block_sync_lds();

        // fragments: row = t*16 + c16 -> swizzle `sw`; byte-in-row g*16+sl*64
        bf16x8 kf[4][2], vf[4][2];
#pragma unroll
        for (int t = 0; t < 4; t++)
#pragma unroll
            for (int sl = 0; sl < 2; sl++) {
                kf[t][sl] = *(const bf16x8*)(KsB[buf] + (t * 16 + c16) * 128 +
                                             ((g * 16 + sl * 64) ^ sw));
                vf[t][sl] = *(const bf16x8*)(VtB[buf] + (t * 16 + c16) * 128 +
                                             ((g * 16 + sl * 64) ^ sw));
            }

#pragma unroll
        for (int qs = 0; qs < 2; qs++) {
            f32x4 s4[4];
#pragma unroll
            for (int t = 0; t < 4; t++) {
                f32x4 acc = {0.f, 0.f, 0.f, 0.f};
                acc = __builtin_amdgcn_mfma_f32_16x16x32_bf16(kf[t][0], qf[qs][0], acc, 0, 0, 0);
                acc = __builtin_amdgcn_mfma_f32_16x16x32_bf16(kf[t][1], qf[qs][1], acc, 0, 0, 0);
                s4[t] = acc;
            }

            float rs = 0.0f;
#pragma unroll
            for (int t = 0; t < 4; t++)
#pragma unroll
                for (int r = 0; r < 4; r++) {
                    float p = __builtin_amdgcn_exp2f(s4[t][r]);
                    const int key = 16 * t + 4 * g + r;
                    p = ((mbits >> key) & 1ull) ? 0.0f : p;
                    s4[t][r] = p;
                    rs += p;
                }
            rs += __shfl_xor(rs, 16);
            rs += __shfl_xor(rs, 32);
            lrow[qs] += rs;

            // P row -> wave-private swizzled strip -> B-fragments
            cfence();
#pragma unroll
            for (int t = 0; t < 4; t++)
#pragma unroll
                for (int rr = 0; rr < 2; rr++) {
                    const uint32_t wv = cvtpk_bf16(s4[t][2 * rr], s4[t][2 * rr + 1]);
                    *(uint32_t*)(PlB[wl] + c16 * 128 +
                                 ((32 * t + 8 * g + 4 * rr) ^ sw)) = wv;
                }
            cfence();
            bf16x8 pa[2];
            pa[0] = *(const bf16x8*)(PlB[wl] + c16 * 128 + ((g * 16) ^ sw));
            pa[1] = *(const bf16x8*)(PlB[wl] + c16 * 128 + ((g * 16 + 64) ^ sw));
            cfence();

#pragma unroll
            for (int td = 0; td < 4; td++) {
                o[qs][td] = __builtin_amdgcn_mfma_f32_16x16x32_bf16(vf[td][0], pa[0], o[qs][td], 0, 0, 0);
                o[qs][td] = __builtin_amdgcn_mfma_f32_16x16x32_bf16(vf[td][1], pa[1], o[qs][td], 0, 0, 0);
            }
        }
    }
#undef ISSUE

#pragma unroll
    for (int qs = 0; qs < 2; qs++) {
        const float inv = 1.0f / lrow[qs];
        const int qq = q0 + wl * 32 + qs * 16 + c16;
#pragma unroll
        for (int td = 0; td < 4; td++) {
            u16x4 hi4, lo4;
#pragma unroll
            for (int r = 0; r < 4; r++) {
                const float val = o[qs][td][r] * inv;
                const unsigned short hv = f2bf(val);
                hi4[r] = hv;
                lo4[r] = f2bf(val - bf2f(hv));
            }
            const size_t idx = ((size_t)b * T + qq) * C + h * DK + td * 16 + 4 * g;
            *(u16x4*)(Xh + idx) = hi4;
            *(u16x4*)(Xl + idx) = lo4;
        }
    }
}

// ---------------------------------------------------------------------------
extern "C" void kernel_launch(void* const* d_in, const int* in_sizes, int n_in,
                              void* d_out, int out_size, void* d_ws, size_t ws_size,
                              hipStream_t stream) {
    const float* query = (const float*)d_in[0];
    const float* key   = (const float*)d_in[1];
    const float* value = (const float*)d_in[2];
    const int*   kpm   = (const int*)d_in[3];
    const float* Wq = (const float*)d_in[4];
    const float* bq = (const float*)d_in[5];
    const float* Wk = (const float*)d_in[6];
    const float* bk = (const float*)d_in[7];
    const float* Wv = (const float*)d_in[8];
    const float* bv = (const float*)d_in[9];
    const float* Wo = (const float*)d_in[10];
    const float* bo = (const float*)d_in[11];

    constexpr size_t MB = 1u << 20;
    char* w8 = (char*)d_ws;
    unsigned short* Qa  = (unsigned short*)(w8 + 0 * MB);   // reused as Xh
    unsigned short* Ka  = (unsigned short*)(w8 + 16 * MB);  // reused as Xl
    unsigned short* Va  = (unsigned short*)(w8 + 32 * MB);
    unsigned short* WB  = (unsigned short*)(w8 + 48 * MB);
    unsigned short* WoH = (unsigned short*)(w8 + 54 * MB);
    unsigned short* WoL = (unsigned short*)(w8 + 56 * MB);
    unsigned short* Qb  = (unsigned short*)(w8 + 64 * MB);
    unsigned short* Kb  = (unsigned short*)(w8 + 80 * MB);
    unsigned short* Vb  = (unsigned short*)(w8 + 96 * MB);
    unsigned short* XhB = Qa;
    unsigned short* XlB = Ka;

    const dim3 blk(256);

    convert_all<<<dim3(14336), blk, 0, stream>>>(query, key, value,
                                                 Wq, Wk, Wv, Wo,
                                                 Qa, Ka, Va, WB, WoH, WoL);

    qkv_gemm<<<dim3(M / 128, 3 * C / 128), blk, 0, stream>>>(Qa, Ka, Va, WB,
                                                             bq, bk, bv,
                                                             Qb, Kb, Vb);

    attn_mfma<<<dim3(T / 128, H, B), blk, 0, stream>>>(Qb, Kb, Vb, kpm, XhB, XlB);

    oproj_gemm<<<dim3(M / 128, C / 128), blk, 0, stream>>>(XhB, XlB, WoH, WoL,
                                                           bo, (float*)d_out);
}

// Round 21
// 254.328 us; speedup vs baseline: 2.9006x; 1.0329x over previous
//
#include <hip/hip_runtime.h>
#include <hip/hip_bf16.h>
#include <cstddef>
#include <cstdint>

constexpr int T  = 2048;
constexpr int B  = 4;
constexpr int C  = 1024;
constexpr int H  = 16;
constexpr int DK = 64;
constexpr int M  = T * B;   // 8192
constexpr int NT = T / 64;  // 32 KV tiles

typedef __attribute__((ext_vector_type(8))) short bf16x8;
typedef __attribute__((ext_vector_type(4))) float f32x4;
typedef __attribute__((ext_vector_type(4))) unsigned short u16x4;
typedef __attribute__((ext_vector_type(8))) unsigned short u16x8;

__device__ inline unsigned short f2bf(float f) {
    union { float f; uint32_t u; } v; v.f = f;
    uint32_t u = v.u + 0x7fff + ((v.u >> 16) & 1);  // RNE
    return (unsigned short)(u >> 16);
}
__device__ inline float bf2f(unsigned short h) {
    union { uint32_t u; float f; } v; v.u = (uint32_t)h << 16;
    return v.f;
}
// HW packed f32->bf16 pair (no builtin on gfx950; T12 recipe)
__device__ inline uint32_t cvtpk_bf16(float lo, float hi) {
    uint32_t r;
    asm("v_cvt_pk_bf16_f32 %0, %1, %2" : "=v"(r) : "v"(lo), "v"(hi));
    return r;
}
// compiler-level full memory fence (no instruction emitted)
__device__ inline void cfence() { asm volatile("" ::: "memory"); }

// Raw workgroup barrier WITHOUT the vmcnt(0) drain __syncthreads emits.
__device__ inline void block_sync_lds() {
    __builtin_amdgcn_sched_barrier(0);
    asm volatile("s_waitcnt lgkmcnt(0)" ::: "memory");
    __builtin_amdgcn_sched_barrier(0);
    __builtin_amdgcn_s_barrier();
    __builtin_amdgcn_sched_barrier(0);
}

// global -> LDS direct DMA, 16B per lane.
__device__ inline void gload_lds16(const void* g, void* l) {
    auto gp = reinterpret_cast<const __attribute__((address_space(1))) char*>(
        reinterpret_cast<uintptr_t>(g));
    auto lp = reinterpret_cast<__attribute__((address_space(3))) char*>(
        reinterpret_cast<uintptr_t>(l));
    __builtin_amdgcn_global_load_lds(gp, lp, 16, 0, 0);
}

// ---------------------------------------------------------------------------
// Unified converter (one launch, R20).
// ---------------------------------------------------------------------------
__global__ __launch_bounds__(256) void convert_all(
        const float* __restrict__ q, const float* __restrict__ k,
        const float* __restrict__ v,
        const float* __restrict__ wq, const float* __restrict__ wk,
        const float* __restrict__ wv, const float* __restrict__ wo,
        unsigned short* __restrict__ dq, unsigned short* __restrict__ dk2,
        unsigned short* __restrict__ dv,
        unsigned short* __restrict__ wb,
        unsigned short* __restrict__ hi, unsigned short* __restrict__ lo) {
    const int bid = blockIdx.x;
    if (bid < 12288) {
        const int which = bid >> 12;            // 0..2
        const int x = bid & 4095;
        const float* s = which == 0 ? q : (which == 1 ? k : v);
        unsigned short* d = which == 0 ? dq : (which == 1 ? dk2 : dv);
        const size_t i = ((size_t)x * 256 + threadIdx.x) * 8;
        const float4 a = *(const float4*)(s + i);
        const float4 b = *(const float4*)(s + i + 4);
        u16x8 o;
        o[0] = f2bf(a.x); o[1] = f2bf(a.y); o[2] = f2bf(a.z); o[3] = f2bf(a.w);
        o[4] = f2bf(b.x); o[5] = f2bf(b.y); o[6] = f2bf(b.z); o[7] = f2bf(b.w);
        *(u16x8*)(d + i) = o;
    } else {
        const int w = bid - 12288;
        const int y = w >> 9;                   // 0..3
        const int x = w & 511;
        const size_t i = ((size_t)x * 256 + threadIdx.x) * 8;
        if (y < 3) {
            const float* s = y == 0 ? wq : (y == 1 ? wk : wv);
            unsigned short* d = wb + (size_t)y * C * C;
            const float4 a = *(const float4*)(s + i);
            const float4 b = *(const float4*)(s + i + 4);
            u16x8 o;
            o[0] = f2bf(a.x); o[1] = f2bf(a.y); o[2] = f2bf(a.z); o[3] = f2bf(a.w);
            o[4] = f2bf(b.x); o[5] = f2bf(b.y); o[6] = f2bf(b.z); o[7] = f2bf(b.w);
            *(u16x8*)(d + i) = o;
        } else {
#pragma unroll
            for (int j = 0; j < 8; j++) {
                const float x2 = wo[i + j];
                const unsigned short h = f2bf(x2);
                hi[i + j] = h;
                lo[i + j] = f2bf(x2 - bf2f(h));
            }
        }
    }
}

// ---------------------------------------------------------------------------
// Fused QKV projection GEMM — R11-exact (at m97-structure ceiling ~900 TF).
// Q scale folds 1/sqrt(DK) * log2(e) for the exp2-based softmax.
// ---------------------------------------------------------------------------
__global__ __launch_bounds__(256) void qkv_gemm(
        const unsigned short* __restrict__ Aq,
        const unsigned short* __restrict__ Ak,
        const unsigned short* __restrict__ Av,
        const unsigned short* __restrict__ W,
        const float* __restrict__ bq, const float* __restrict__ bk,
        const float* __restrict__ bv,
        unsigned short* __restrict__ Qb, unsigned short* __restrict__ Kb,
        unsigned short* __restrict__ Vb) {
    __shared__ __align__(16) unsigned short As[128][32];
    __shared__ __align__(16) unsigned short Ws[128][32];

    const int tid = threadIdx.x;
    const int m0 = blockIdx.x * 128;
    const int n0 = blockIdx.y * 128;
    const int w = tid >> 6, lane = tid & 63;
    const int g = lane >> 4, c16 = lane & 15;
    const int wr = (w >> 1) * 64, wc = (w & 1) * 64;

    const int which = n0 >> 10;  // 0=Q 1=K 2=V (no straddle)
    const unsigned short* A = which == 0 ? Aq : (which == 1 ? Ak : Av);

    f32x4 acc[4][4] = {};

    for (int k0 = 0; k0 < C; k0 += 32) {
        __syncthreads();
#pragma unroll
        for (int half = 0; half < 2; half++) {
            const int chunk = tid + half * 256;       // 0..511
            const int r = chunk >> 2, s = chunk & 3;  // row, 16B slot
            gload_lds16(A + (size_t)(m0 + r) * C + k0 + s * 8,
                        (char*)&As[0][0] + chunk * 16);
            gload_lds16(W + (size_t)(n0 + r) * C + k0 + s * 8,
                        (char*)&Ws[0][0] + chunk * 16);
        }
        __syncthreads();

        bf16x8 af[4], bfr[4];
#pragma unroll
        for (int mf = 0; mf < 4; mf++)
            af[mf] = *(const bf16x8*)&As[wr + mf * 16 + c16][g * 8];
#pragma unroll
        for (int nf = 0; nf < 4; nf++)
            bfr[nf] = *(const bf16x8*)&Ws[wc + nf * 16 + c16][g * 8];
#pragma unroll
        for (int mf = 0; mf < 4; mf++)
#pragma unroll
            for (int nf = 0; nf < 4; nf++)
                acc[mf][nf] = __builtin_amdgcn_mfma_f32_16x16x32_bf16(
                    af[mf], bfr[nf], acc[mf][nf], 0, 0, 0);
    }

    unsigned short* dst = which == 0 ? Qb : (which == 1 ? Kb : Vb);
    const float* bias = which == 0 ? bq : (which == 1 ? bk : bv);
    const float scale = which == 0 ? 0.180336889f : 1.0f;  // 0.125*log2(e) | 1

#pragma unroll
    for (int mf = 0; mf < 4; mf++) {
#pragma unroll
        for (int nf = 0; nf < 4; nf++) {
            const int n = n0 + wc + nf * 16 + c16;
            const int c = n & 1023;
            const int hh = c >> 6, dk = c & 63;
            const float bval = bias[c];
#pragma unroll
            for (int r = 0; r < 4; r++) {
                const int m = m0 + wr + mf * 16 + g * 4 + r;
                const int t = m >> 2, bb = m & 3;             // m = t*B + b
                dst[((size_t)(bb * H + hh) * T + t) * DK + dk] =
                    f2bf((acc[mf][nf][r] + bval) * scale);
            }
        }
    }
}

// ---------------------------------------------------------------------------
// Output projection, bf16x3 (R7/R11 passing structure).
// ---------------------------------------------------------------------------
__global__ __launch_bounds__(256) void oproj_gemm(
        const unsigned short* __restrict__ Xh, const unsigned short* __restrict__ Xl,
        const unsigned short* __restrict__ Wh, const unsigned short* __restrict__ Wl,
        const float* __restrict__ bo, float* __restrict__ out) {
    __shared__ __align__(16) unsigned short Ahs[128][32];
    __shared__ __align__(16) unsigned short Als[128][32];
    __shared__ __align__(16) unsigned short Bhs[128][32];
    __shared__ __align__(16) unsigned short Bls[128][32];

    const int tid = threadIdx.x;
    const int m0 = blockIdx.x * 128;
    const int n0 = blockIdx.y * 128;
    const int w = tid >> 6, lane = tid & 63;
    const int g = lane >> 4, c16 = lane & 15;
    const int wr = (w >> 1) * 64, wc = (w & 1) * 64;

    f32x4 acc[4][4] = {};

    for (int k0 = 0; k0 < C; k0 += 32) {
        __syncthreads();
#pragma unroll
        for (int half = 0; half < 2; half++) {
            const int chunk = tid + half * 256;
            const int r = chunk >> 2, s = chunk & 3;
            const size_t goffA = (size_t)(m0 + r) * C + k0 + s * 8;
            const size_t goffB = (size_t)(n0 + r) * C + k0 + s * 8;
            gload_lds16(Xh + goffA, (char*)&Ahs[0][0] + chunk * 16);
            gload_lds16(Xl + goffA, (char*)&Als[0][0] + chunk * 16);
            gload_lds16(Wh + goffB, (char*)&Bhs[0][0] + chunk * 16);
            gload_lds16(Wl + goffB, (char*)&Bls[0][0] + chunk * 16);
        }
        __syncthreads();

        bf16x8 ah[4], al[4];
#pragma unroll
        for (int mf = 0; mf < 4; mf++) {
            ah[mf] = *(const bf16x8*)&Ahs[wr + mf * 16 + c16][g * 8];
            al[mf] = *(const bf16x8*)&Als[wr + mf * 16 + c16][g * 8];
        }
#pragma unroll
        for (int nf = 0; nf < 4; nf++) {
            const bf16x8 wh = *(const bf16x8*)&Bhs[wc + nf * 16 + c16][g * 8];
            const bf16x8 wl = *(const bf16x8*)&Bls[wc + nf * 16 + c16][g * 8];
#pragma unroll
            for (int mf = 0; mf < 4; mf++) {
                acc[mf][nf] = __builtin_amdgcn_mfma_f32_16x16x32_bf16(ah[mf], wh, acc[mf][nf], 0, 0, 0);
                acc[mf][nf] = __builtin_amdgcn_mfma_f32_16x16x32_bf16(al[mf], wh, acc[mf][nf], 0, 0, 0);
                acc[mf][nf] = __builtin_amdgcn_mfma_f32_16x16x32_bf16(ah[mf], wl, acc[mf][nf], 0, 0, 0);
            }
        }
    }

#pragma unroll
    for (int mf = 0; mf < 4; mf++) {
#pragma unroll
        for (int nf = 0; nf < 4; nf++) {
            const int n = n0 + wc + nf * 16 + c16;
            const float bval = bo[n];
#pragma unroll
            for (int r = 0; r < 4; r++) {
                const int m = m0 + wr + mf * 16 + g * 4 + r;  // m = b*T + t
                const int t = m & 2047, bb = m >> 11;
                out[((size_t)t * B + bb) * C + n] = acc[mf][nf][r] + bval;
            }
        }
    }
}

// ---------------------------------------------------------------------------
// Flash attention v11 = R19 champion inner loop with QBLK 128 -> 256
// (8 waves / 512 threads). Same K/V tile now serves 2x the q-rows: per-thread
// staging halves (K: 1 uint4; V: 4 u32 from 2 u16x4 loads). Inner compute,
// swizzle contract, read-side indices, mask ballot (lane = tid&63, identical
// per wave) and epilogue are unchanged. LDS 48 KB -> 3 blocks/CU; grid = 512
// blocks = exactly 2/CU (VGPR cap), no tail.
// V-map check: dv2 = tid>>5 (0..15), rows dv2*4+j (j 0..3) cover 0..63 once;
// row&7 = (dv2&1)*4+j matches read-side swizzle (c16&7)<<4 contract.
// ---------------------------------------------------------------------------
__global__ __launch_bounds__(512) void attn_mfma(const unsigned short* __restrict__ Q,
                                                 const unsigned short* __restrict__ K,
                                                 const unsigned short* __restrict__ V,
                                                 const int* __restrict__ mask,
                                                 unsigned short* __restrict__ Xh,
                                                 unsigned short* __restrict__ Xl) {
    __shared__ __align__(16) char KsB[2][8192];   // [64 rows][128 B] swizzled
    __shared__ __align__(16) char VtB[2][8192];   // transposed V, swizzled
    __shared__ __align__(16) char PlB[8][2048];   // per-wave [16 rows][128 B]

    const int b = blockIdx.z, h = blockIdx.y;
    const int q0 = blockIdx.x * 256;
    const int tid = threadIdx.x;
    const int wl = tid >> 6;          // wave 0..7
    const int lane = tid & 63;
    const int g = lane >> 4;
    const int c16 = lane & 15;
    const int sw = (c16 & 7) << 4;    // read-side swizzle (row&7 == c16&7)

    const size_t bh = (size_t)(b * H + h) * T * DK;
    const unsigned short* Qg = Q + bh;
    const unsigned short* Kg = K + bh;
    const unsigned short* Vg = V + bh;
    const int* mb = mask + b * T;

    bf16x8 qf[2][2];
#pragma unroll
    for (int qs = 0; qs < 2; qs++)
#pragma unroll
        for (int sl = 0; sl < 2; sl++)
            qf[qs][sl] = *(const bf16x8*)(Qg +
                (size_t)(q0 + wl * 32 + qs * 16 + c16) * DK + g * 8 + sl * 32);

    f32x4 o[2][4] = {};
    float lrow[2] = {0.0f, 0.0f};

    // staging maps (512 threads)
    const int skr = tid >> 3;          // K row 0..63
    const int skb = (tid & 7) * 16;    // K byte-in-row (16B slot)
    const int swk = (skr & 7) << 4;    // K write swizzle
    const int kp = tid & 31;           // V key-pair 0..31
    const int dv2 = tid >> 5;          // V row-group 0..15 (4 rows each)
    uint4 kra; u16x4 va4, vb4; int mw;

#define ISSUE(kv0)                                                              \
    do {                                                                        \
        kra = *(const uint4*)(Kg + (size_t)((kv0) + skr) * DK + (skb >> 1));    \
        va4 = *(const u16x4*)(Vg + (size_t)((kv0) + 2 * kp) * DK + dv2 * 4);    \
        vb4 = *(const u16x4*)(Vg + (size_t)((kv0) + 2 * kp + 1) * DK + dv2 * 4); \
        mw  = mb[(kv0) + lane];                                                 \
    } while (0)

    ISSUE(0);

    for (int kt = 0; kt < NT; ++kt) {
        const int buf = kt & 1;

        const unsigned long long mbits = __ballot(mw != 0);
        // K: one swizzled 16B slot per thread
        *(uint4*)(KsB[buf] + skr * 128 + (skb ^ swk)) = kra;
        // V transposed: rows dv2*4+j (row&7 = (dv2&1)*4+j), u32 at byte 4*kp
#pragma unroll
        for (int j = 0; j < 4; j++) {
            const int row = dv2 * 4 + j;
            *(uint32_t*)(VtB[buf] + row * 128 + ((4 * kp) ^ ((row & 7) << 4))) =
                (uint32_t)(unsigned short)va4[j] | ((uint32_t)(unsigned short)vb4[j] << 16);
        }
        if (kt + 1 < NT) ISSUE((kt + 1) * 64);

        block_sync_lds();

        // fragments: row = t*16 + c16 -> swizzle `sw`; byte-in-row g*16+sl*64
        bf16x8 kf[4][2], vf[4][2];
#pragma unroll
        for (int t = 0; t < 4; t++)
#pragma unroll
            for (int sl = 0; sl < 2; sl++) {
                kf[t][sl] = *(const bf16x8*)(KsB[buf] + (t * 16 + c16) * 128 +
                                             ((g * 16 + sl * 64) ^ sw));
                vf[t][sl] = *(const bf16x8*)(VtB[buf] + (t * 16 + c16) * 128 +
                                             ((g * 16 + sl * 64) ^ sw));
            }

#pragma unroll
        for (int qs = 0; qs < 2; qs++) {
            f32x4 s4[4];
#pragma unroll
            for (int t = 0; t < 4; t++) {
                f32x4 acc = {0.f, 0.f, 0.f, 0.f};
                acc = __builtin_amdgcn_mfma_f32_16x16x32_bf16(kf[t][0], qf[qs][0], acc, 0, 0, 0);
                acc = __builtin_amdgcn_mfma_f32_16x16x32_bf16(kf[t][1], qf[qs][1], acc, 0, 0, 0);
                s4[t] = acc;
            }

            float rs = 0.0f;
#pragma unroll
            for (int t = 0; t < 4; t++)
#pragma unroll
                for (int r = 0; r < 4; r++) {
                    float p = __builtin_amdgcn_exp2f(s4[t][r]);
                    const int key = 16 * t + 4 * g + r;
                    p = ((mbits >> key) & 1ull) ? 0.0f : p;
                    s4[t][r] = p;
                    rs += p;
                }
            rs += __shfl_xor(rs, 16);
            rs += __shfl_xor(rs, 32);
            lrow[qs] += rs;

            // P row -> wave-private swizzled strip -> B-fragments
            cfence();
#pragma unroll
            for (int t = 0; t < 4; t++)
#pragma unroll
                for (int rr = 0; rr < 2; rr++) {
                    const uint32_t wv = cvtpk_bf16(s4[t][2 * rr], s4[t][2 * rr + 1]);
                    *(uint32_t*)(PlB[wl] + c16 * 128 +
                                 ((32 * t + 8 * g + 4 * rr) ^ sw)) = wv;
                }
            cfence();
            bf16x8 pa[2];
            pa[0] = *(const bf16x8*)(PlB[wl] + c16 * 128 + ((g * 16) ^ sw));
            pa[1] = *(const bf16x8*)(PlB[wl] + c16 * 128 + ((g * 16 + 64) ^ sw));
            cfence();

#pragma unroll
            for (int td = 0; td < 4; td++) {
                o[qs][td] = __builtin_amdgcn_mfma_f32_16x16x32_bf16(vf[td][0], pa[0], o[qs][td], 0, 0, 0);
                o[qs][td] = __builtin_amdgcn_mfma_f32_16x16x32_bf16(vf[td][1], pa[1], o[qs][td], 0, 0, 0);
            }
        }
    }
#undef ISSUE

#pragma unroll
    for (int qs = 0; qs < 2; qs++) {
        const float inv = 1.0f / lrow[qs];
        const int qq = q0 + wl * 32 + qs * 16 + c16;
#pragma unroll
        for (int td = 0; td < 4; td++) {
            u16x4 hi4, lo4;
#pragma unroll
            for (int r = 0; r < 4; r++) {
                const float val = o[qs][td][r] * inv;
                const unsigned short hv = f2bf(val);
                hi4[r] = hv;
                lo4[r] = f2bf(val - bf2f(hv));
            }
            const size_t idx = ((size_t)b * T + qq) * C + h * DK + td * 16 + 4 * g;
            *(u16x4*)(Xh + idx) = hi4;
            *(u16x4*)(Xl + idx) = lo4;
        }
    }
}

// ---------------------------------------------------------------------------
extern "C" void kernel_launch(void* const* d_in, const int* in_sizes, int n_in,
                              void* d_out, int out_size, void* d_ws, size_t ws_size,
                              hipStream_t stream) {
    const float* query = (const float*)d_in[0];
    const float* key   = (const float*)d_in[1];
    const float* value = (const float*)d_in[2];
    const int*   kpm   = (const int*)d_in[3];
    const float* Wq = (const float*)d_in[4];
    const float* bq = (const float*)d_in[5];
    const float* Wk = (const float*)d_in[6];
    const float* bk = (const float*)d_in[7];
    const float* Wv = (const float*)d_in[8];
    const float* bv = (const float*)d_in[9];
    const float* Wo = (const float*)d_in[10];
    const float* bo = (const float*)d_in[11];

    constexpr size_t MB = 1u << 20;
    char* w8 = (char*)d_ws;
    unsigned short* Qa  = (unsigned short*)(w8 + 0 * MB);   // reused as Xh
    unsigned short* Ka  = (unsigned short*)(w8 + 16 * MB);  // reused as Xl
    unsigned short* Va  = (unsigned short*)(w8 + 32 * MB);
    unsigned short* WB  = (unsigned short*)(w8 + 48 * MB);
    unsigned short* WoH = (unsigned short*)(w8 + 54 * MB);
    unsigned short* WoL = (unsigned short*)(w8 + 56 * MB);
    unsigned short* Qb  = (unsigned short*)(w8 + 64 * MB);
    unsigned short* Kb  = (unsigned short*)(w8 + 80 * MB);
    unsigned short* Vb  = (unsigned short*)(w8 + 96 * MB);
    unsigned short* XhB = Qa;
    unsigned short* XlB = Ka;

    const dim3 blk(256);

    convert_all<<<dim3(14336), blk, 0, stream>>>(query, key, value,
                                                 Wq, Wk, Wv, Wo,
                                                 Qa, Ka, Va, WB, WoH, WoL);

    qkv_gemm<<<dim3(M / 128, 3 * C / 128), blk, 0, stream>>>(Qa, Ka, Va, WB,
                                                             bq, bk, bv,
                                                             Qb, Kb, Vb);

    attn_mfma<<<dim3(T / 256, H, B), dim3(512), 0, stream>>>(Qb, Kb, Vb, kpm,
                                                             XhB, XlB);

    oproj_gemm<<<dim3(M / 128, C / 128), blk, 0, stream>>>(XhB, XlB, WoH, WoL,
                                                           bo, (float*)d_out);
}